// Round 7
// baseline (1032.661 us; speedup 1.0000x reference)
//
#include <hip/hip_runtime.h>
#include <hip/hip_bf16.h>
#include <stdint.h>

static constexpr int BATCH = 256;

#define CDIV(a,b) (((a)+(b)-1)/(b))

// ---------------- weight packing ----------------
__global__ void k_pack_conv_w(const float* __restrict__ w, uint32_t* __restrict__ out, int Co, int CW){
  int idx = blockIdx.x*256 + threadIdx.x;
  int total = Co*CW*9;
  if (idx >= total) return;
  int tap = idx % 9; int t = idx / 9; int cw = t % CW; int co = t / CW;
  int Ci = CW*32;
  const float* src = w + ((size_t)co*Ci + (size_t)cw*32)*9 + tap;
  uint32_t bits = 0;
  #pragma unroll
  for (int b=0;b<32;b++) bits |= (src[(size_t)b*9] >= 0.f ? 1u:0u) << b;
  out[idx] = bits;
}

__global__ void k_pack_fc1_w(const float* __restrict__ w, uint32_t* __restrict__ out){
  int idx = blockIdx.x*256 + threadIdx.x;
  if (idx >= 1024*256) return;
  int wd = idx & 255, o = idx >> 8;
  int cw = wd >> 4, p = wd & 15;
  const float* src = w + (size_t)o*8192;
  uint32_t bits=0;
  #pragma unroll
  for (int b=0;b<32;b++) bits |= (src[(cw*32+b)*16 + p] >= 0.f ? 1u:0u) << b;
  out[idx]=bits;
}

__global__ void k_pack_fc2_w(const float* __restrict__ w, uint32_t* __restrict__ out){
  int idx = blockIdx.x*256+threadIdx.x; if (idx >= 10*32) return;
  int wd = idx & 31, o = idx >> 5;
  uint32_t bits=0;
  #pragma unroll
  for (int b=0;b<32;b++) bits |= (w[o*1024 + wd*32 + b] >= 0.f ? 1u:0u)<<b;
  out[idx]=bits;
}

// =====================================================================
// conv1: x[n,3,32,32] (real) * sign(w1)[128,3,3,3]. f64-exact.
// Block = (n, rowgroup of 8 rows). LDS: x slice [3][10][34] f64 (halo'd,
// zero-padded) + w1 [128][27] f32 (conflict-free: stride 27, gcd(27,32)=1).
// Wave layout: lane = channel (c0 + lane), waves split {c-half, row-half}.
// =====================================================================

// stats: each lane accumulates s,s2 for its channel over 4 rows x 32 px.
__global__ __launch_bounds__(256) void k_conv1_stats3(const float* __restrict__ x,
        const float* __restrict__ w1, double* __restrict__ partials){
  __shared__ double xs[3][10][34];
  __shared__ float wf[128][27];
  int n = blockIdx.x >> 2, rg = blockIdx.x & 3;
  int y0 = rg*8;
  const float* xp = x + (size_t)n*3*1024;
  for (int i=threadIdx.x; i<3*10*34; i+=256){
    int ci = i/340, r = i%340, ly = r/34, lx = r%34;
    int gy = y0 - 1 + ly, gx = lx - 1;
    double v = 0.0;
    if (gy>=0 && gy<32 && gx>=0 && gx<32) v = (double)xp[ci*1024 + gy*32 + gx];
    (&xs[0][0][0])[i] = v;
  }
  for (int i=threadIdx.x; i<128*27; i+=256)
    (&wf[0][0])[i] = w1[i];
  __syncthreads();
  int wave = threadIdx.x>>6, lane = threadIdx.x&63;
  int c0 = (wave&1)*64, rsub = wave>>1;
  int co = c0 + lane;
  double w[27];
  #pragma unroll
  for (int k=0;k<27;k++) w[k] = (wf[co][k] >= 0.f) ? 1.0 : -1.0;
  double s=0.0, s2=0.0;
  for (int rr = rsub*4; rr < rsub*4+4; ++rr){
    for (int xx=0; xx<32; ++xx){
      double a0=0.0, a1=0.0, a2=0.0;
      #pragma unroll
      for (int ci=0;ci<3;ci++){
        const double* r0 = &xs[ci][rr+0][xx];
        const double* r1 = &xs[ci][rr+1][xx];
        const double* r2 = &xs[ci][rr+2][xx];
        a0 += r0[0]*w[ci*9+0] + r0[1]*w[ci*9+1] + r0[2]*w[ci*9+2];
        a1 += r1[0]*w[ci*9+3] + r1[1]*w[ci*9+4] + r1[2]*w[ci*9+5];
        a2 += r2[0]*w[ci*9+6] + r2[1]*w[ci*9+7] + r2[2]*w[ci*9+8];
      }
      double acc = (a0 + a1) + a2;
      s += acc; s2 += acc*acc;
    }
  }
  size_t pi = (size_t)co*2048 + (size_t)n*8 + rg*2 + rsub;
  partials[pi*2+0]=s; partials[pi*2+1]=s2;
}

__global__ void k_finalize_partials(const double* __restrict__ partials, const float* __restrict__ g,
                                    const float* __restrict__ b, double* __restrict__ A, double* __restrict__ Bv,
                                    int C, int nPart, double invCount){
  int c = blockIdx.x*64+threadIdx.x; if (c>=C) return;
  double S=0,S2=0;
  for (int i=0;i<nPart;i++){ S+=partials[((size_t)c*nPart+i)*2]; S2+=partials[((size_t)c*nPart+i)*2+1]; }
  double m = S*invCount;
  double v = S2*invCount - m*m;
  double a = (double)g[c] / sqrt(v + 1e-5);
  A[c]=a; Bv[c] = (double)b[c] - m*a;
}

// binarize: same structure; per-pixel __ballot packs 64 lane-decisions,
// staged in wordbuf, coalesced copy out.
__global__ __launch_bounds__(256) void k_conv1_binarize4(const float* __restrict__ x,
        const float* __restrict__ w1, const double* __restrict__ A, const double* __restrict__ Bv,
        uint32_t* __restrict__ bits){
  __shared__ double xs[3][10][34];
  __shared__ float wf[128][27];
  __shared__ uint32_t wordbuf[4][256];
  int n = blockIdx.x >> 2, rg = blockIdx.x & 3;
  int y0 = rg*8;
  const float* xp = x + (size_t)n*3*1024;
  for (int i=threadIdx.x; i<3*10*34; i+=256){
    int ci = i/340, r = i%340, ly = r/34, lx = r%34;
    int gy = y0 - 1 + ly, gx = lx - 1;
    double v = 0.0;
    if (gy>=0 && gy<32 && gx>=0 && gx<32) v = (double)xp[ci*1024 + gy*32 + gx];
    (&xs[0][0][0])[i] = v;
  }
  for (int i=threadIdx.x; i<128*27; i+=256)
    (&wf[0][0])[i] = w1[i];
  __syncthreads();
  int wave = threadIdx.x>>6, lane = threadIdx.x&63;
  int c0 = (wave&1)*64, rsub = wave>>1;
  int co = c0 + lane;
  double w[27];
  #pragma unroll
  for (int k=0;k<27;k++) w[k] = (wf[co][k] >= 0.f) ? 1.0 : -1.0;
  double av = A[co], bv = Bv[co];
  for (int rr = rsub*4; rr < rsub*4+4; ++rr){
    for (int xx=0; xx<32; ++xx){
      double a0=0.0, a1=0.0, a2=0.0;
      #pragma unroll
      for (int ci=0;ci<3;ci++){
        const double* r0 = &xs[ci][rr+0][xx];
        const double* r1 = &xs[ci][rr+1][xx];
        const double* r2 = &xs[ci][rr+2][xx];
        a0 += r0[0]*w[ci*9+0] + r0[1]*w[ci*9+1] + r0[2]*w[ci*9+2];
        a1 += r1[0]*w[ci*9+3] + r1[1]*w[ci*9+4] + r1[2]*w[ci*9+5];
        a2 += r2[0]*w[ci*9+6] + r2[1]*w[ci*9+7] + r2[2]*w[ci*9+8];
      }
      double acc = (a0 + a1) + a2;
      int pred = (acc*av + bv >= 0.0) ? 1 : 0;
      unsigned long long m = __ballot(pred);
      if (lane == 0){
        wordbuf[(c0>>5)+0][rr*32+xx] = (uint32_t)m;
        wordbuf[(c0>>5)+1][rr*32+xx] = (uint32_t)(m>>32);
      }
    }
  }
  __syncthreads();
  for (int i=threadIdx.x; i<1024; i+=256){
    int cw = i>>8, p = i&255;
    bits[(size_t)n*4096 + cw*1024 + rg*256 + p] = wordbuf[cw][p];
  }
}

// =====================================================================
// LDS-tiled XNOR conv
// =====================================================================
template<int CW,int H,int W,int CO,int COB,int NX>
__global__ __launch_bounds__(256) void k_xconv_pool(const uint32_t* __restrict__ in,
        const uint32_t* __restrict__ wb, int16_t* __restrict__ out){
  constexpr int PITCH = W+1;
  constexpr int WP = CW*9+1;
  constexpr int NG = CO/COB;
  constexpr int XS = W/NX;
  constexpr int UNITS = (H/2)*XS;
  static_assert(COB*UNITS==256, "thread mapping");
  __shared__ uint32_t inlds[CW*H*PITCH];
  __shared__ uint32_t wlds[COB*WP];
  __shared__ int colpc[COB][10];
  int n = blockIdx.x / NG, cg = blockIdx.x % NG;
  int co0 = cg*COB;
  const uint32_t* ip = in + (size_t)n*CW*H*W;
  for (int i=threadIdx.x; i<CW*H*W; i+=256){
    int cw = i/(H*W); int r = i%(H*W); int y=r/W, x=r%W;
    inlds[cw*H*PITCH + y*PITCH + x] = ip[i];
  }
  for (int i=threadIdx.x; i<COB*CW*9; i+=256){
    int co = i/(CW*9); int r = i%(CW*9);
    wlds[co*WP + r] = wb[(size_t)(co0+co)*CW*9 + r];
  }
  __syncthreads();
  for (int i=threadIdx.x; i<COB*9; i+=256){
    int co=i/9, tap=i%9; int s=0;
    #pragma unroll
    for (int cw=0;cw<CW;cw++) s += __popc(wlds[co*WP + cw*9 + tap]);
    colpc[co][tap]=s;
  }
  __syncthreads();
  int t = threadIdx.x;
  int col = t / UNITS;
  int rem = t % UNITS;
  int yy = rem / XS;
  int xs = (rem % XS)*NX;
  int co = co0 + col;
  int acc0[NX], acc1[NX];
  #pragma unroll
  for (int i2=0;i2<NX;i2++){acc0[i2]=0;acc1[i2]=0;}
  for (int cw=0; cw<CW; cw++){
    uint32_t wr[9];
    #pragma unroll
    for (int k=0;k<9;k++) wr[k]=wlds[col*WP+cw*9+k];
    uint32_t rr[4][NX+2];
    #pragma unroll
    for (int rrow=0; rrow<4; rrow++){
      int y = 2*yy-1+rrow;
      int yc = y<0?0:(y>H-1?H-1:y);
      bool yv = (y>=0)&&(y<H);
      #pragma unroll
      for (int j=0;j<NX+2;j++){
        int x = xs-1+j;
        int xc = x<0?0:(x>W-1?W-1:x);
        uint32_t v = inlds[cw*H*PITCH + yc*PITCH + xc];
        rr[rrow][j] = (yv && x>=0 && x<W) ? v : 0u;
      }
    }
    #pragma unroll
    for (int q=0;q<NX;q++){
      int a0 = __popc(rr[0][q]^wr[0])+__popc(rr[0][q+1]^wr[1])+__popc(rr[0][q+2]^wr[2])
             + __popc(rr[1][q]^wr[3])+__popc(rr[1][q+1]^wr[4])+__popc(rr[1][q+2]^wr[5])
             + __popc(rr[2][q]^wr[6])+__popc(rr[2][q+1]^wr[7])+__popc(rr[2][q+2]^wr[8]);
      int a1 = __popc(rr[1][q]^wr[0])+__popc(rr[1][q+1]^wr[1])+__popc(rr[1][q+2]^wr[2])
             + __popc(rr[2][q]^wr[3])+__popc(rr[2][q+1]^wr[4])+__popc(rr[2][q+2]^wr[5])
             + __popc(rr[3][q]^wr[6])+__popc(rr[3][q+1]^wr[7])+__popc(rr[3][q+2]^wr[8]);
      acc0[q]+=a0; acc1[q]+=a1;
    }
  }
  const int* cp = colpc[col];
  int16_t res[NX/2];
  #pragma unroll
  for (int tp=0; tp<NX/2; tp++){
    int best=-32768;
    #pragma unroll
    for (int rrow=0;rrow<2;rrow++){
      int kyi = (rrow==0 && yy==0) ? 0 : ((rrow==1 && yy==H/2-1) ? 2 : -1);
      #pragma unroll
      for (int dx=0;dx<2;dx++){
        int q = 2*tp+dx;
        int x = xs+q;
        int kxi = (x==0)?0:((x==W-1)?2:-1);
        int acc = rrow? acc1[q]:acc0[q];
        int corr=0, nv=9;
        if (kyi>=0){ corr += cp[kyi*3+0]+cp[kyi*3+1]+cp[kyi*3+2]; }
        if (kxi>=0){ corr += cp[0+kxi]+cp[3+kxi]+cp[6+kxi]; }
        if (kyi>=0 && kxi>=0){ corr -= cp[kyi*3+kxi]; nv=4; }
        else if (kyi>=0 || kxi>=0) nv=6;
        int dot = 32*CW*nv - 2*(acc - corr);
        best = dot>best?dot:best;
      }
    }
    res[tp]=(int16_t)best;
  }
  int16_t* op = out + (((size_t)n*CO + co)*(H/2) + yy)*(W/2) + xs/2;
  #pragma unroll
  for (int tp=0;tp<NX/2;tp++) op[tp]=res[tp];
}

template<int CW,int H,int W,int CO,int COB,int NX>
__global__ __launch_bounds__(256) void k_xconv(const uint32_t* __restrict__ in,
        const uint32_t* __restrict__ wb, int16_t* __restrict__ out){
  constexpr int PITCH = W+1;
  constexpr int WP = CW*9+1;
  constexpr int NG = CO/COB;
  constexpr int XS = W/NX;
  constexpr int UNITS = H*XS;
  static_assert((COB/2)*UNITS==256, "thread mapping");
  __shared__ uint32_t inlds[CW*H*PITCH];
  __shared__ uint32_t wlds[COB*WP];
  __shared__ int colpc[COB][10];
  int n = blockIdx.x / NG, cg = blockIdx.x % NG;
  int co0 = cg*COB;
  const uint32_t* ip = in + (size_t)n*CW*H*W;
  for (int i=threadIdx.x; i<CW*H*W; i+=256){
    int cw = i/(H*W); int r = i%(H*W); int y=r/W, x=r%W;
    inlds[cw*H*PITCH + y*PITCH + x] = ip[i];
  }
  for (int i=threadIdx.x; i<COB*CW*9; i+=256){
    int co = i/(CW*9); int r = i%(CW*9);
    wlds[co*WP + r] = wb[(size_t)(co0+co)*CW*9 + r];
  }
  __syncthreads();
  for (int i=threadIdx.x; i<COB*9; i+=256){
    int co=i/9, tap=i%9; int s=0;
    #pragma unroll
    for (int cw=0;cw<CW;cw++) s += __popc(wlds[co*WP + cw*9 + tap]);
    colpc[co][tap]=s;
  }
  __syncthreads();
  int t = threadIdx.x;
  int cog = t / UNITS;
  int rem = t % UNITS;
  int y = rem / XS;
  int xs = (rem % XS)*NX;
  int c0 = cog*2;
  int acc[2][NX];
  #pragma unroll
  for (int c=0;c<2;c++)
    #pragma unroll
    for (int i2=0;i2<NX;i2++) acc[c][i2]=0;
  for (int cw=0; cw<CW; cw++){
    uint32_t wr[2][9];
    #pragma unroll
    for (int c=0;c<2;c++)
      #pragma unroll
      for (int k=0;k<9;k++) wr[c][k]=wlds[(c0+c)*WP+cw*9+k];
    uint32_t rr[3][NX+2];
    #pragma unroll
    for (int rrow=0; rrow<3; rrow++){
      int yr = y-1+rrow;
      int yc = yr<0?0:(yr>H-1?H-1:yr);
      bool yv = (yr>=0)&&(yr<H);
      #pragma unroll
      for (int j=0;j<NX+2;j++){
        int x = xs-1+j;
        int xc = x<0?0:(x>W-1?W-1:x);
        uint32_t v = inlds[cw*H*PITCH + yc*PITCH + xc];
        rr[rrow][j] = (yv && x>=0 && x<W) ? v : 0u;
      }
    }
    #pragma unroll
    for (int q=0;q<NX;q++){
      #pragma unroll
      for (int c=0;c<2;c++){
        int a = __popc(rr[0][q]^wr[c][0])+__popc(rr[0][q+1]^wr[c][1])+__popc(rr[0][q+2]^wr[c][2])
              + __popc(rr[1][q]^wr[c][3])+__popc(rr[1][q+1]^wr[c][4])+__popc(rr[1][q+2]^wr[c][5])
              + __popc(rr[2][q]^wr[c][6])+__popc(rr[2][q+1]^wr[c][7])+__popc(rr[2][q+2]^wr[c][8]);
        acc[c][q]+=a;
      }
    }
  }
  int kyi = (y==0)?0:((y==H-1)?2:-1);
  #pragma unroll
  for (int c=0;c<2;c++){
    const int* cp = colpc[c0+c];
    int16_t rbuf[NX];
    #pragma unroll
    for (int q=0;q<NX;q++){
      int x = xs+q;
      int kxi = (x==0)?0:((x==W-1)?2:-1);
      int corr=0, nv=9;
      if (kyi>=0){ corr += cp[kyi*3+0]+cp[kyi*3+1]+cp[kyi*3+2]; }
      if (kxi>=0){ corr += cp[0+kxi]+cp[3+kxi]+cp[6+kxi]; }
      if (kyi>=0 && kxi>=0){ corr -= cp[kyi*3+kxi]; nv=4; }
      else if (kyi>=0 || kxi>=0) nv=6;
      rbuf[q] = (int16_t)(32*CW*nv - 2*(acc[c][q] - corr));
    }
    int16_t* op = out + (((size_t)n*CO + (co0+c0+c))*H + y)*W + xs;
    #pragma unroll
    for (int q=0;q<NX;q++) op[q]=rbuf[q];
  }
}

// ---------------- per-channel BN stats, exact int64, 2-stage ----------------
template<int NP>
__global__ void k_chstats_part(const int16_t* __restrict__ in, long long* __restrict__ part,
                               int C, int HW){
  int c = blockIdx.x / NP, p = blockIdx.x % NP;
  const int NPB = BATCH/NP;
  long long s=0, s2=0;
  int total = NPB*HW;
  for (int i=threadIdx.x; i<total; i+=256){
    int n = p*NPB + i/HW; int hw = i%HW;
    int v = in[((size_t)n*C+c)*HW+hw];
    s += v; s2 += (long long)(v*v);
  }
  __shared__ long long sh[8];
  for (int off=32; off; off>>=1){ s+=__shfl_down(s,off,64); s2+=__shfl_down(s2,off,64); }
  int wid=threadIdx.x>>6, lane=threadIdx.x&63;
  if(lane==0){sh[wid]=s;sh[4+wid]=s2;}
  __syncthreads();
  if(threadIdx.x==0){
    long long S=0,S2=0;
    #pragma unroll
    for(int i=0;i<4;i++){S+=sh[i];S2+=sh[4+i];}
    part[((size_t)c*NP+p)*2+0]=S;
    part[((size_t)c*NP+p)*2+1]=S2;
  }
}

__global__ void k_chstats_fin(const long long* __restrict__ part, const float* __restrict__ g,
                              const float* __restrict__ b, double* __restrict__ A, double* __restrict__ Bv,
                              int C, int NP, double invCount){
  int c = blockIdx.x*64+threadIdx.x; if (c>=C) return;
  long long S=0,S2=0;
  for (int i=0;i<NP;i++){ S+=part[((size_t)c*NP+i)*2]; S2+=part[((size_t)c*NP+i)*2+1]; }
  double m = (double)S*invCount;
  double v = (double)S2*invCount - m*m;
  double a = (double)g[c]/sqrt(v+1e-5);
  A[c]=a; Bv[c]=(double)b[c]-m*a;
}

// ---------------- binarize BN(conv) and pack ----------------
__global__ void k_binarize_pack(const int16_t* __restrict__ in, const double* __restrict__ A,
                                const double* __restrict__ Bv, uint32_t* __restrict__ bits,
                                int C, int HW){
  int CW = C>>5;
  size_t total = (size_t)BATCH*CW*HW;
  size_t idx = (size_t)blockIdx.x*256+threadIdx.x;
  if (idx>=total) return;
  int hw = (int)(idx % HW); size_t t = idx/HW;
  int cw = (int)(t % CW); int n = (int)(t / CW);
  uint32_t wordv=0;
  for (int b=0;b<32;b++){
    int c = cw*32+b;
    double v = (double)in[((size_t)n*C + c)*HW + hw];
    if (v*A[c]+Bv[c] >= 0.0) wordv |= 1u<<b;
  }
  bits[idx]=wordv;
}

// ---------------- FC1 ----------------
__global__ void k_fc1(const uint32_t* __restrict__ actbits, const uint32_t* __restrict__ wb,
                      int16_t* __restrict__ out){
  int og = blockIdx.x & 3; int n = blockIdx.x >> 2;
  int o = og*256 + threadIdx.x;
  __shared__ uint32_t sact[256];
  sact[threadIdx.x] = actbits[(size_t)n*256 + threadIdx.x];
  __syncthreads();
  const uint32_t* wp = wb + (size_t)o*256;
  int acc=0;
  #pragma unroll 8
  for (int k=0;k<256;k++) acc += __popc(sact[k]^wp[k]);
  out[(size_t)n*1024 + o] = (int16_t)(8192 - 2*acc);
}

__global__ void k_fc_stats(const int16_t* __restrict__ in, const float* __restrict__ g,
                           const float* __restrict__ b, double* __restrict__ A, double* __restrict__ Bv){
  int f = blockIdx.x;
  double v = (double)in[(size_t)threadIdx.x*1024 + f];
  double s=v, s2=v*v;
  __shared__ double sh[8];
  for (int off=32; off; off>>=1){ s+=__shfl_down(s,off,64); s2+=__shfl_down(s2,off,64); }
  int wid=threadIdx.x>>6, lane=threadIdx.x&63;
  if(lane==0){sh[wid]=s;sh[4+wid]=s2;}
  __syncthreads();
  if(threadIdx.x==0){
    double S=0,S2=0;
    #pragma unroll
    for(int i=0;i<4;i++){S+=sh[i];S2+=sh[4+i];}
    double m=S/256.0, var=S2/256.0-m*m;
    double a=(double)g[f]/sqrt(var+1e-5);
    A[f]=a; Bv[f]=(double)b[f]-m*a;
  }
}

__global__ void k_binpack_fc(const int16_t* __restrict__ in, const double* __restrict__ A,
                             const double* __restrict__ Bv, uint32_t* __restrict__ bits){
  int idx = blockIdx.x*256+threadIdx.x;
  if (idx >= 256*32) return;
  int w = idx & 31, n = idx >> 5;
  uint32_t word=0;
  for (int b=0;b<32;b++){
    int f = w*32+b;
    double v=(double)in[(size_t)n*1024+f];
    if (v*A[f]+Bv[f] >= 0.0) word|=1u<<b;
  }
  bits[idx]=word;
}

// ---------------- FC2 + final BN -> float out ----------------
__global__ void k_fc2_out(const uint32_t* __restrict__ actbits, const uint32_t* __restrict__ wb,
                          const float* __restrict__ bias2, const float* __restrict__ g,
                          const float* __restrict__ b, float* __restrict__ out){
  int o = blockIdx.x;     // 0..9
  int n = threadIdx.x;    // 0..255
  const uint32_t* ap = actbits + (size_t)n*32;
  const uint32_t* wp = wb + (size_t)o*32;
  int acc=0;
  #pragma unroll
  for (int k=0;k<32;k++) acc += __popc(ap[k]^wp[k]);
  double h = (double)(1024 - 2*acc) + (double)bias2[o];
  double s=h, s2=h*h;
  __shared__ double sh[8];
  for(int off=32;off;off>>=1){s+=__shfl_down(s,off,64);s2+=__shfl_down(s2,off,64);}
  int wid=threadIdx.x>>6,lane=threadIdx.x&63;
  if(lane==0){sh[wid]=s;sh[4+wid]=s2;}
  __syncthreads();
  __shared__ double sm, sinv;
  if(threadIdx.x==0){
    double S=0,S2=0;
    #pragma unroll
    for(int i=0;i<4;i++){S+=sh[i];S2+=sh[4+i];}
    double m=S/256.0, v=S2/256.0-m*m;
    sm=m; sinv=1.0/sqrt(v+1e-5);
  }
  __syncthreads();
  double r = (h - sm)*sinv*(double)g[o] + (double)b[o];
  out[(size_t)n*10 + o] = (float)r;
}

extern "C" void kernel_launch(void* const* d_in, const int* in_sizes, int n_in,
                              void* d_out, int out_size, void* d_ws, size_t ws_size,
                              hipStream_t stream) {
  const float* x   = (const float*)d_in[0];
  const float* w1  = (const float*)d_in[1];
  const float* g1  = (const float*)d_in[2];
  const float* b1  = (const float*)d_in[3];
  const float* w2  = (const float*)d_in[4];
  const float* g2  = (const float*)d_in[5];
  const float* b2  = (const float*)d_in[6];
  const float* w3  = (const float*)d_in[7];
  const float* g3  = (const float*)d_in[8];
  const float* b3  = (const float*)d_in[9];
  const float* w4  = (const float*)d_in[10];
  const float* g4  = (const float*)d_in[11];
  const float* b4  = (const float*)d_in[12];
  const float* w5  = (const float*)d_in[13];
  const float* g5  = (const float*)d_in[14];
  const float* b5  = (const float*)d_in[15];
  const float* w6  = (const float*)d_in[16];
  const float* g6  = (const float*)d_in[17];
  const float* b6  = (const float*)d_in[18];
  const float* wf1 = (const float*)d_in[19];
  const float* gf1 = (const float*)d_in[20];
  const float* bf1 = (const float*)d_in[21];
  const float* wf2 = (const float*)d_in[22];
  const float* bias2=(const float*)d_in[23];
  const float* gf2 = (const float*)d_in[24];
  const float* bf2 = (const float*)d_in[25];
  float* out = (float*)d_out;

  char* ws = (char*)d_ws;
  size_t off = 0;
  auto alloc = [&](size_t bytes)->char*{ char* p = ws + off; off = (off + bytes + 255) & ~(size_t)255; return p; };

  uint32_t* wb2  = (uint32_t*)alloc(4608ull*4);
  uint32_t* wb3  = (uint32_t*)alloc(9216ull*4);
  uint32_t* wb4  = (uint32_t*)alloc(18432ull*4);
  uint32_t* wb5  = (uint32_t*)alloc(36864ull*4);
  uint32_t* wb6  = (uint32_t*)alloc(73728ull*4);
  uint32_t* wf1b = (uint32_t*)alloc(262144ull*4);
  uint32_t* wf2b = (uint32_t*)alloc(320ull*4);
  double*   part = (double*)  alloc(128ull*2048*2*8);
  long long* pll = (long long*)alloc(512ull*8*2*8);
  double*   Abuf = (double*)  alloc(1024ull*8);
  double*   Bbuf = (double*)  alloc(1024ull*8);
  uint32_t* bitsA= (uint32_t*)alloc(1048576ull*4);
  uint32_t* bitsB= (uint32_t*)alloc(262144ull*4);
  int16_t*  conv = (int16_t*) alloc(16777216ull*2);

  // pack weights
  k_pack_conv_w<<<CDIV(4608,256),256,0,stream>>>(w2, wb2, 128, 4);
  k_pack_conv_w<<<CDIV(9216,256),256,0,stream>>>(w3, wb3, 256, 4);
  k_pack_conv_w<<<CDIV(18432,256),256,0,stream>>>(w4, wb4, 256, 8);
  k_pack_conv_w<<<CDIV(36864,256),256,0,stream>>>(w5, wb5, 512, 8);
  k_pack_conv_w<<<CDIV(73728,256),256,0,stream>>>(w6, wb6, 512, 16);
  k_pack_fc1_w<<<CDIV(262144,256),256,0,stream>>>(wf1, wf1b);
  k_pack_fc2_w<<<CDIV(320,256),256,0,stream>>>(wf2, wf2b);

  // ---- layer 1 ----
  k_conv1_stats3<<<1024,256,0,stream>>>(x, w1, part);
  k_finalize_partials<<<CDIV(128,64),64,0,stream>>>(part, g1, b1, Abuf, Bbuf, 128, 2048, 1.0/(256.0*1024.0));
  k_conv1_binarize4<<<1024,256,0,stream>>>(x, w1, Abuf, Bbuf, bitsA);

  // ---- layer 2: conv+pool -> [256,128,16,16] ----
  k_xconv_pool<4,32,32,128,4,8><<<256*32,256,0,stream>>>(bitsA, wb2, conv);
  k_chstats_part<8><<<128*8,256,0,stream>>>(conv, pll, 128, 256);
  k_chstats_fin<<<CDIV(128,64),64,0,stream>>>(pll, g2, b2, Abuf, Bbuf, 128, 8, 1.0/(256.0*256.0));
  k_binarize_pack<<<CDIV(256ull*4*256,256),256,0,stream>>>(conv, Abuf, Bbuf, bitsB, 128, 256);

  // ---- layer 3: conv -> [256,256,16,16] ----
  k_xconv<4,16,16,256,16,8><<<256*16,256,0,stream>>>(bitsB, wb3, conv);
  k_chstats_part<8><<<256*8,256,0,stream>>>(conv, pll, 256, 256);
  k_chstats_fin<<<CDIV(256,64),64,0,stream>>>(pll, g3, b3, Abuf, Bbuf, 256, 8, 1.0/(256.0*256.0));
  k_binarize_pack<<<CDIV(256ull*8*256,256),256,0,stream>>>(conv, Abuf, Bbuf, bitsA, 256, 256);

  // ---- layer 4: conv+pool -> [256,256,8,8] ----
  k_xconv_pool<8,16,16,256,16,8><<<256*16,256,0,stream>>>(bitsA, wb4, conv);
  k_chstats_part<8><<<256*8,256,0,stream>>>(conv, pll, 256, 64);
  k_chstats_fin<<<CDIV(256,64),64,0,stream>>>(pll, g4, b4, Abuf, Bbuf, 256, 8, 1.0/(256.0*64.0));
  k_binarize_pack<<<CDIV(256ull*8*64,256),256,0,stream>>>(conv, Abuf, Bbuf, bitsB, 256, 64);

  // ---- layer 5: conv -> [256,512,8,8] ----
  k_xconv<8,8,8,512,64,8><<<256*8,256,0,stream>>>(bitsB, wb5, conv);
  k_chstats_part<8><<<512*8,256,0,stream>>>(conv, pll, 512, 64);
  k_chstats_fin<<<CDIV(512,64),64,0,stream>>>(pll, g5, b5, Abuf, Bbuf, 512, 8, 1.0/(256.0*64.0));
  k_binarize_pack<<<CDIV(256ull*16*64,256),256,0,stream>>>(conv, Abuf, Bbuf, bitsA, 512, 64);

  // ---- layer 6: conv+pool -> [256,512,4,4] ----
  k_xconv_pool<16,8,8,512,64,8><<<256*8,256,0,stream>>>(bitsA, wb6, conv);
  k_chstats_part<8><<<512*8,256,0,stream>>>(conv, pll, 512, 16);
  k_chstats_fin<<<CDIV(512,64),64,0,stream>>>(pll, g6, b6, Abuf, Bbuf, 512, 8, 1.0/(256.0*16.0));
  k_binarize_pack<<<CDIV(256ull*16*16,256),256,0,stream>>>(conv, Abuf, Bbuf, bitsB, 512, 16);

  // ---- FC1 ----
  k_fc1<<<256*4,256,0,stream>>>(bitsB, wf1b, conv);
  k_fc_stats<<<1024,256,0,stream>>>(conv, gf1, bf1, Abuf, Bbuf);
  k_binpack_fc<<<CDIV(256*32,256),256,0,stream>>>(conv, Abuf, Bbuf, bitsA);

  // ---- FC2 + final BN ----
  k_fc2_out<<<10,256,0,stream>>>(bitsA, wf2b, bias2, gf2, bf2, out);

  (void)in_sizes; (void)n_in; (void)out_size; (void)ws_size;
}

// Round 8
// 802.255 us; speedup vs baseline: 1.2872x; 1.2872x over previous
//
#include <hip/hip_runtime.h>
#include <hip/hip_bf16.h>
#include <stdint.h>

static constexpr int BATCH = 256;

#define CDIV(a,b) (((a)+(b)-1)/(b))

// ---------------- weight packing ----------------
__global__ void k_pack_conv_w(const float* __restrict__ w, uint32_t* __restrict__ out, int Co, int CW){
  int idx = blockIdx.x*256 + threadIdx.x;
  int total = Co*CW*9;
  if (idx >= total) return;
  int tap = idx % 9; int t = idx / 9; int cw = t % CW; int co = t / CW;
  int Ci = CW*32;
  const float* src = w + ((size_t)co*Ci + (size_t)cw*32)*9 + tap;
  uint32_t bits = 0;
  #pragma unroll
  for (int b=0;b<32;b++) bits |= (src[(size_t)b*9] >= 0.f ? 1u:0u) << b;
  out[idx] = bits;
}

__global__ void k_pack_fc1_w(const float* __restrict__ w, uint32_t* __restrict__ out){
  int idx = blockIdx.x*256 + threadIdx.x;
  if (idx >= 1024*256) return;
  int wd = idx & 255, o = idx >> 8;
  int cw = wd >> 4, p = wd & 15;
  const float* src = w + (size_t)o*8192;
  uint32_t bits=0;
  #pragma unroll
  for (int b=0;b<32;b++) bits |= (src[(cw*32+b)*16 + p] >= 0.f ? 1u:0u) << b;
  out[idx]=bits;
}

__global__ void k_pack_fc2_w(const float* __restrict__ w, uint32_t* __restrict__ out){
  int idx = blockIdx.x*256+threadIdx.x; if (idx >= 10*32) return;
  int wd = idx & 31, o = idx >> 5;
  uint32_t bits=0;
  #pragma unroll
  for (int b=0;b<32;b++) bits |= (w[o*1024 + wd*32 + b] >= 0.f ? 1u:0u)<<b;
  out[idx]=bits;
}

// =====================================================================
// conv1: x[n,3,32,32] (real) * sign(w1)[128,3,3,3]. f64-exact.
// Block = (n, rowgroup of 8 rows). LDS: x slice [3][10][34] f64 (halo'd,
// zero-padded) + w1 [128][27] f32. Wave: lane = channel.
// =====================================================================

__global__ __launch_bounds__(256) void k_conv1_stats3(const float* __restrict__ x,
        const float* __restrict__ w1, double* __restrict__ partials){
  __shared__ double xs[3][10][34];
  __shared__ float wf[128][27];
  int n = blockIdx.x >> 2, rg = blockIdx.x & 3;
  int y0 = rg*8;
  const float* xp = x + (size_t)n*3*1024;
  for (int i=threadIdx.x; i<3*10*34; i+=256){
    int ci = i/340, r = i%340, ly = r/34, lx = r%34;
    int gy = y0 - 1 + ly, gx = lx - 1;
    double v = 0.0;
    if (gy>=0 && gy<32 && gx>=0 && gx<32) v = (double)xp[ci*1024 + gy*32 + gx];
    (&xs[0][0][0])[i] = v;
  }
  for (int i=threadIdx.x; i<128*27; i+=256)
    (&wf[0][0])[i] = w1[i];
  __syncthreads();
  int wave = threadIdx.x>>6, lane = threadIdx.x&63;
  int c0 = (wave&1)*64, rsub = wave>>1;
  int co = c0 + lane;
  double w[27];
  #pragma unroll
  for (int k=0;k<27;k++) w[k] = (wf[co][k] >= 0.f) ? 1.0 : -1.0;
  double s=0.0, s2=0.0;
  for (int rr = rsub*4; rr < rsub*4+4; ++rr){
    for (int xx=0; xx<32; ++xx){
      double a0=0.0, a1=0.0, a2=0.0;
      #pragma unroll
      for (int ci=0;ci<3;ci++){
        const double* r0 = &xs[ci][rr+0][xx];
        const double* r1 = &xs[ci][rr+1][xx];
        const double* r2 = &xs[ci][rr+2][xx];
        a0 += r0[0]*w[ci*9+0] + r0[1]*w[ci*9+1] + r0[2]*w[ci*9+2];
        a1 += r1[0]*w[ci*9+3] + r1[1]*w[ci*9+4] + r1[2]*w[ci*9+5];
        a2 += r2[0]*w[ci*9+6] + r2[1]*w[ci*9+7] + r2[2]*w[ci*9+8];
      }
      double acc = (a0 + a1) + a2;
      s += acc; s2 += acc*acc;
    }
  }
  size_t pi = (size_t)co*2048 + (size_t)n*8 + rg*2 + rsub;
  partials[pi*2+0]=s; partials[pi*2+1]=s2;
}

// parallel finalize: 1 block per channel, strided coalesced loads + reduce
__global__ __launch_bounds__(256) void k_finalize_partials_p(const double* __restrict__ partials,
        const float* __restrict__ g, const float* __restrict__ b,
        double* __restrict__ A, double* __restrict__ Bv, int nPart, double invCount){
  int c = blockIdx.x;
  double s=0.0, s2=0.0;
  for (int i=threadIdx.x; i<nPart; i+=256){
    s  += partials[((size_t)c*nPart+i)*2+0];
    s2 += partials[((size_t)c*nPart+i)*2+1];
  }
  for (int off=32; off; off>>=1){ s+=__shfl_down(s,off,64); s2+=__shfl_down(s2,off,64); }
  __shared__ double sh[8];
  int wid=threadIdx.x>>6, lane=threadIdx.x&63;
  if(lane==0){sh[wid]=s;sh[4+wid]=s2;}
  __syncthreads();
  if(threadIdx.x==0){
    double S=0,S2=0;
    #pragma unroll
    for(int i=0;i<4;i++){S+=sh[i];S2+=sh[4+i];}
    double m=S*invCount, v=S2*invCount-m*m;
    double a=(double)g[c]/sqrt(v+1e-5);
    A[c]=a; Bv[c]=(double)b[c]-m*a;
  }
}

// binarize: per-pixel __ballot packs 64 lane-decisions.
__global__ __launch_bounds__(256) void k_conv1_binarize4(const float* __restrict__ x,
        const float* __restrict__ w1, const double* __restrict__ A, const double* __restrict__ Bv,
        uint32_t* __restrict__ bits){
  __shared__ double xs[3][10][34];
  __shared__ float wf[128][27];
  __shared__ uint32_t wordbuf[4][256];
  int n = blockIdx.x >> 2, rg = blockIdx.x & 3;
  int y0 = rg*8;
  const float* xp = x + (size_t)n*3*1024;
  for (int i=threadIdx.x; i<3*10*34; i+=256){
    int ci = i/340, r = i%340, ly = r/34, lx = r%34;
    int gy = y0 - 1 + ly, gx = lx - 1;
    double v = 0.0;
    if (gy>=0 && gy<32 && gx>=0 && gx<32) v = (double)xp[ci*1024 + gy*32 + gx];
    (&xs[0][0][0])[i] = v;
  }
  for (int i=threadIdx.x; i<128*27; i+=256)
    (&wf[0][0])[i] = w1[i];
  __syncthreads();
  int wave = threadIdx.x>>6, lane = threadIdx.x&63;
  int c0 = (wave&1)*64, rsub = wave>>1;
  int co = c0 + lane;
  double w[27];
  #pragma unroll
  for (int k=0;k<27;k++) w[k] = (wf[co][k] >= 0.f) ? 1.0 : -1.0;
  double av = A[co], bv = Bv[co];
  for (int rr = rsub*4; rr < rsub*4+4; ++rr){
    for (int xx=0; xx<32; ++xx){
      double a0=0.0, a1=0.0, a2=0.0;
      #pragma unroll
      for (int ci=0;ci<3;ci++){
        const double* r0 = &xs[ci][rr+0][xx];
        const double* r1 = &xs[ci][rr+1][xx];
        const double* r2 = &xs[ci][rr+2][xx];
        a0 += r0[0]*w[ci*9+0] + r0[1]*w[ci*9+1] + r0[2]*w[ci*9+2];
        a1 += r1[0]*w[ci*9+3] + r1[1]*w[ci*9+4] + r1[2]*w[ci*9+5];
        a2 += r2[0]*w[ci*9+6] + r2[1]*w[ci*9+7] + r2[2]*w[ci*9+8];
      }
      double acc = (a0 + a1) + a2;
      int pred = (acc*av + bv >= 0.0) ? 1 : 0;
      unsigned long long m = __ballot(pred);
      if (lane == 0){
        wordbuf[(c0>>5)+0][rr*32+xx] = (uint32_t)m;
        wordbuf[(c0>>5)+1][rr*32+xx] = (uint32_t)(m>>32);
      }
    }
  }
  __syncthreads();
  for (int i=threadIdx.x; i<1024; i+=256){
    int cw = i>>8, p = i&255;
    bits[(size_t)n*4096 + cw*1024 + rg*256 + p] = wordbuf[cw][p];
  }
}

// =====================================================================
// LDS-tiled XNOR conv
// =====================================================================
template<int CW,int H,int W,int CO,int COB,int NX>
__global__ __launch_bounds__(256) void k_xconv_pool(const uint32_t* __restrict__ in,
        const uint32_t* __restrict__ wb, int16_t* __restrict__ out){
  constexpr int PITCH = W+1;
  constexpr int WP = CW*9+1;
  constexpr int NG = CO/COB;
  constexpr int XS = W/NX;
  constexpr int UNITS = (H/2)*XS;
  static_assert(COB*UNITS==256, "thread mapping");
  __shared__ uint32_t inlds[CW*H*PITCH];
  __shared__ uint32_t wlds[COB*WP];
  __shared__ int colpc[COB][10];
  int n = blockIdx.x / NG, cg = blockIdx.x % NG;
  int co0 = cg*COB;
  const uint32_t* ip = in + (size_t)n*CW*H*W;
  for (int i=threadIdx.x; i<CW*H*W; i+=256){
    int cw = i/(H*W); int r = i%(H*W); int y=r/W, x=r%W;
    inlds[cw*H*PITCH + y*PITCH + x] = ip[i];
  }
  for (int i=threadIdx.x; i<COB*CW*9; i+=256){
    int co = i/(CW*9); int r = i%(CW*9);
    wlds[co*WP + r] = wb[(size_t)(co0+co)*CW*9 + r];
  }
  __syncthreads();
  for (int i=threadIdx.x; i<COB*9; i+=256){
    int co=i/9, tap=i%9; int s=0;
    #pragma unroll
    for (int cw=0;cw<CW;cw++) s += __popc(wlds[co*WP + cw*9 + tap]);
    colpc[co][tap]=s;
  }
  __syncthreads();
  int t = threadIdx.x;
  int col = t / UNITS;
  int rem = t % UNITS;
  int yy = rem / XS;
  int xs = (rem % XS)*NX;
  int co = co0 + col;
  int acc0[NX], acc1[NX];
  #pragma unroll
  for (int i2=0;i2<NX;i2++){acc0[i2]=0;acc1[i2]=0;}
  for (int cw=0; cw<CW; cw++){
    uint32_t wr[9];
    #pragma unroll
    for (int k=0;k<9;k++) wr[k]=wlds[col*WP+cw*9+k];
    uint32_t rr[4][NX+2];
    #pragma unroll
    for (int rrow=0; rrow<4; rrow++){
      int y = 2*yy-1+rrow;
      int yc = y<0?0:(y>H-1?H-1:y);
      bool yv = (y>=0)&&(y<H);
      #pragma unroll
      for (int j=0;j<NX+2;j++){
        int x = xs-1+j;
        int xc = x<0?0:(x>W-1?W-1:x);
        uint32_t v = inlds[cw*H*PITCH + yc*PITCH + xc];
        rr[rrow][j] = (yv && x>=0 && x<W) ? v : 0u;
      }
    }
    #pragma unroll
    for (int q=0;q<NX;q++){
      int a0 = __popc(rr[0][q]^wr[0])+__popc(rr[0][q+1]^wr[1])+__popc(rr[0][q+2]^wr[2])
             + __popc(rr[1][q]^wr[3])+__popc(rr[1][q+1]^wr[4])+__popc(rr[1][q+2]^wr[5])
             + __popc(rr[2][q]^wr[6])+__popc(rr[2][q+1]^wr[7])+__popc(rr[2][q+2]^wr[8]);
      int a1 = __popc(rr[1][q]^wr[0])+__popc(rr[1][q+1]^wr[1])+__popc(rr[1][q+2]^wr[2])
             + __popc(rr[2][q]^wr[3])+__popc(rr[2][q+1]^wr[4])+__popc(rr[2][q+2]^wr[5])
             + __popc(rr[3][q]^wr[6])+__popc(rr[3][q+1]^wr[7])+__popc(rr[3][q+2]^wr[8]);
      acc0[q]+=a0; acc1[q]+=a1;
    }
  }
  const int* cp = colpc[col];
  int16_t res[NX/2];
  #pragma unroll
  for (int tp=0; tp<NX/2; tp++){
    int best=-32768;
    #pragma unroll
    for (int rrow=0;rrow<2;rrow++){
      int kyi = (rrow==0 && yy==0) ? 0 : ((rrow==1 && yy==H/2-1) ? 2 : -1);
      #pragma unroll
      for (int dx=0;dx<2;dx++){
        int q = 2*tp+dx;
        int x = xs+q;
        int kxi = (x==0)?0:((x==W-1)?2:-1);
        int acc = rrow? acc1[q]:acc0[q];
        int corr=0, nv=9;
        if (kyi>=0){ corr += cp[kyi*3+0]+cp[kyi*3+1]+cp[kyi*3+2]; }
        if (kxi>=0){ corr += cp[0+kxi]+cp[3+kxi]+cp[6+kxi]; }
        if (kyi>=0 && kxi>=0){ corr -= cp[kyi*3+kxi]; nv=4; }
        else if (kyi>=0 || kxi>=0) nv=6;
        int dot = 32*CW*nv - 2*(acc - corr);
        best = dot>best?dot:best;
      }
    }
    res[tp]=(int16_t)best;
  }
  int16_t* op = out + (((size_t)n*CO + co)*(H/2) + yy)*(W/2) + xs/2;
  #pragma unroll
  for (int tp=0;tp<NX/2;tp++) op[tp]=res[tp];
}

template<int CW,int H,int W,int CO,int COB,int NX>
__global__ __launch_bounds__(256) void k_xconv(const uint32_t* __restrict__ in,
        const uint32_t* __restrict__ wb, int16_t* __restrict__ out){
  constexpr int PITCH = W+1;
  constexpr int WP = CW*9+1;
  constexpr int NG = CO/COB;
  constexpr int XS = W/NX;
  constexpr int UNITS = H*XS;
  static_assert((COB/2)*UNITS==256, "thread mapping");
  __shared__ uint32_t inlds[CW*H*PITCH];
  __shared__ uint32_t wlds[COB*WP];
  __shared__ int colpc[COB][10];
  int n = blockIdx.x / NG, cg = blockIdx.x % NG;
  int co0 = cg*COB;
  const uint32_t* ip = in + (size_t)n*CW*H*W;
  for (int i=threadIdx.x; i<CW*H*W; i+=256){
    int cw = i/(H*W); int r = i%(H*W); int y=r/W, x=r%W;
    inlds[cw*H*PITCH + y*PITCH + x] = ip[i];
  }
  for (int i=threadIdx.x; i<COB*CW*9; i+=256){
    int co = i/(CW*9); int r = i%(CW*9);
    wlds[co*WP + r] = wb[(size_t)(co0+co)*CW*9 + r];
  }
  __syncthreads();
  for (int i=threadIdx.x; i<COB*9; i+=256){
    int co=i/9, tap=i%9; int s=0;
    #pragma unroll
    for (int cw=0;cw<CW;cw++) s += __popc(wlds[co*WP + cw*9 + tap]);
    colpc[co][tap]=s;
  }
  __syncthreads();
  int t = threadIdx.x;
  int cog = t / UNITS;
  int rem = t % UNITS;
  int y = rem / XS;
  int xs = (rem % XS)*NX;
  int c0 = cog*2;
  int acc[2][NX];
  #pragma unroll
  for (int c=0;c<2;c++)
    #pragma unroll
    for (int i2=0;i2<NX;i2++) acc[c][i2]=0;
  for (int cw=0; cw<CW; cw++){
    uint32_t wr[2][9];
    #pragma unroll
    for (int c=0;c<2;c++)
      #pragma unroll
      for (int k=0;k<9;k++) wr[c][k]=wlds[(c0+c)*WP+cw*9+k];
    uint32_t rr[3][NX+2];
    #pragma unroll
    for (int rrow=0; rrow<3; rrow++){
      int yr = y-1+rrow;
      int yc = yr<0?0:(yr>H-1?H-1:yr);
      bool yv = (yr>=0)&&(yr<H);
      #pragma unroll
      for (int j=0;j<NX+2;j++){
        int x = xs-1+j;
        int xc = x<0?0:(x>W-1?W-1:x);
        uint32_t v = inlds[cw*H*PITCH + yc*PITCH + xc];
        rr[rrow][j] = (yv && x>=0 && x<W) ? v : 0u;
      }
    }
    #pragma unroll
    for (int q=0;q<NX;q++){
      #pragma unroll
      for (int c=0;c<2;c++){
        int a = __popc(rr[0][q]^wr[c][0])+__popc(rr[0][q+1]^wr[c][1])+__popc(rr[0][q+2]^wr[c][2])
              + __popc(rr[1][q]^wr[c][3])+__popc(rr[1][q+1]^wr[c][4])+__popc(rr[1][q+2]^wr[c][5])
              + __popc(rr[2][q]^wr[c][6])+__popc(rr[2][q+1]^wr[c][7])+__popc(rr[2][q+2]^wr[c][8]);
        acc[c][q]+=a;
      }
    }
  }
  int kyi = (y==0)?0:((y==H-1)?2:-1);
  #pragma unroll
  for (int c=0;c<2;c++){
    const int* cp = colpc[c0+c];
    int16_t rbuf[NX];
    #pragma unroll
    for (int q=0;q<NX;q++){
      int x = xs+q;
      int kxi = (x==0)?0:((x==W-1)?2:-1);
      int corr=0, nv=9;
      if (kyi>=0){ corr += cp[kyi*3+0]+cp[kyi*3+1]+cp[kyi*3+2]; }
      if (kxi>=0){ corr += cp[0+kxi]+cp[3+kxi]+cp[6+kxi]; }
      if (kyi>=0 && kxi>=0){ corr -= cp[kyi*3+kxi]; nv=4; }
      else if (kyi>=0 || kxi>=0) nv=6;
      rbuf[q] = (int16_t)(32*CW*nv - 2*(acc[c][q] - corr));
    }
    int16_t* op = out + (((size_t)n*CO + (co0+c0+c))*H + y)*W + xs;
    #pragma unroll
    for (int q=0;q<NX;q++) op[q]=rbuf[q];
  }
}

// ---------------- per-channel BN stats, exact int64, 2-stage ----------------
template<int NP>
__global__ void k_chstats_part(const int16_t* __restrict__ in, long long* __restrict__ part,
                               int C, int HW){
  int c = blockIdx.x / NP, p = blockIdx.x % NP;
  const int NPB = BATCH/NP;
  long long s=0, s2=0;
  int total = NPB*HW;
  for (int i=threadIdx.x; i<total; i+=256){
    int n = p*NPB + i/HW; int hw = i%HW;
    int v = in[((size_t)n*C+c)*HW+hw];
    s += v; s2 += (long long)(v*v);
  }
  __shared__ long long sh[8];
  for (int off=32; off; off>>=1){ s+=__shfl_down(s,off,64); s2+=__shfl_down(s2,off,64); }
  int wid=threadIdx.x>>6, lane=threadIdx.x&63;
  if(lane==0){sh[wid]=s;sh[4+wid]=s2;}
  __syncthreads();
  if(threadIdx.x==0){
    long long S=0,S2=0;
    #pragma unroll
    for(int i=0;i<4;i++){S+=sh[i];S2+=sh[4+i];}
    part[((size_t)c*NP+p)*2+0]=S;
    part[((size_t)c*NP+p)*2+1]=S2;
  }
}

__global__ void k_chstats_fin(const long long* __restrict__ part, const float* __restrict__ g,
                              const float* __restrict__ b, double* __restrict__ A, double* __restrict__ Bv,
                              int C, int NP, double invCount){
  int c = blockIdx.x*64+threadIdx.x; if (c>=C) return;
  long long S=0,S2=0;
  for (int i=0;i<NP;i++){ S+=part[((size_t)c*NP+i)*2]; S2+=part[((size_t)c*NP+i)*2+1]; }
  double m = (double)S*invCount;
  double v = (double)S2*invCount - m*m;
  double a = (double)g[c]/sqrt(v+1e-5);
  A[c]=a; Bv[c]=(double)b[c]-m*a;
}

// ---------------- binarize BN(conv) and pack ----------------
__global__ void k_binarize_pack(const int16_t* __restrict__ in, const double* __restrict__ A,
                                const double* __restrict__ Bv, uint32_t* __restrict__ bits,
                                int C, int HW){
  int CW = C>>5;
  size_t total = (size_t)BATCH*CW*HW;
  size_t idx = (size_t)blockIdx.x*256+threadIdx.x;
  if (idx>=total) return;
  int hw = (int)(idx % HW); size_t t = idx/HW;
  int cw = (int)(t % CW); int n = (int)(t / CW);
  uint32_t wordv=0;
  for (int b=0;b<32;b++){
    int c = cw*32+b;
    double v = (double)in[((size_t)n*C + c)*HW + hw];
    if (v*A[c]+Bv[c] >= 0.0) wordv |= 1u<<b;
  }
  bits[idx]=wordv;
}

// ---------------- FC1 ----------------
__global__ void k_fc1(const uint32_t* __restrict__ actbits, const uint32_t* __restrict__ wb,
                      int16_t* __restrict__ out){
  int og = blockIdx.x & 3; int n = blockIdx.x >> 2;
  int o = og*256 + threadIdx.x;
  __shared__ uint32_t sact[256];
  sact[threadIdx.x] = actbits[(size_t)n*256 + threadIdx.x];
  __syncthreads();
  const uint32_t* wp = wb + (size_t)o*256;
  int acc=0;
  #pragma unroll 8
  for (int k=0;k<256;k++) acc += __popc(sact[k]^wp[k]);
  out[(size_t)n*1024 + o] = (int16_t)(8192 - 2*acc);
}

__global__ void k_fc_stats(const int16_t* __restrict__ in, const float* __restrict__ g,
                           const float* __restrict__ b, double* __restrict__ A, double* __restrict__ Bv){
  int f = blockIdx.x;
  double v = (double)in[(size_t)threadIdx.x*1024 + f];
  double s=v, s2=v*v;
  __shared__ double sh[8];
  for (int off=32; off; off>>=1){ s+=__shfl_down(s,off,64); s2+=__shfl_down(s2,off,64); }
  int wid=threadIdx.x>>6, lane=threadIdx.x&63;
  if(lane==0){sh[wid]=s;sh[4+wid]=s2;}
  __syncthreads();
  if(threadIdx.x==0){
    double S=0,S2=0;
    #pragma unroll
    for(int i=0;i<4;i++){S+=sh[i];S2+=sh[4+i];}
    double m=S/256.0, var=S2/256.0-m*m;
    double a=(double)g[f]/sqrt(var+1e-5);
    A[f]=a; Bv[f]=(double)b[f]-m*a;
  }
}

__global__ void k_binpack_fc(const int16_t* __restrict__ in, const double* __restrict__ A,
                             const double* __restrict__ Bv, uint32_t* __restrict__ bits){
  int idx = blockIdx.x*256+threadIdx.x;
  if (idx >= 256*32) return;
  int w = idx & 31, n = idx >> 5;
  uint32_t word=0;
  for (int b=0;b<32;b++){
    int f = w*32+b;
    double v=(double)in[(size_t)n*1024+f];
    if (v*A[f]+Bv[f] >= 0.0) word|=1u<<b;
  }
  bits[idx]=word;
}

// ---------------- FC2 + final BN -> float out ----------------
__global__ void k_fc2_out(const uint32_t* __restrict__ actbits, const uint32_t* __restrict__ wb,
                          const float* __restrict__ bias2, const float* __restrict__ g,
                          const float* __restrict__ b, float* __restrict__ out){
  int o = blockIdx.x;     // 0..9
  int n = threadIdx.x;    // 0..255
  const uint32_t* ap = actbits + (size_t)n*32;
  const uint32_t* wp = wb + (size_t)o*32;
  int acc=0;
  #pragma unroll
  for (int k=0;k<32;k++) acc += __popc(ap[k]^wp[k]);
  double h = (double)(1024 - 2*acc) + (double)bias2[o];
  double s=h, s2=h*h;
  __shared__ double sh[8];
  for(int off=32;off;off>>=1){s+=__shfl_down(s,off,64);s2+=__shfl_down(s2,off,64);}
  int wid=threadIdx.x>>6,lane=threadIdx.x&63;
  if(lane==0){sh[wid]=s;sh[4+wid]=s2;}
  __syncthreads();
  __shared__ double sm, sinv;
  if(threadIdx.x==0){
    double S=0,S2=0;
    #pragma unroll
    for(int i=0;i<4;i++){S+=sh[i];S2+=sh[4+i];}
    double m=S/256.0, v=S2/256.0-m*m;
    sm=m; sinv=1.0/sqrt(v+1e-5);
  }
  __syncthreads();
  double r = (h - sm)*sinv*(double)g[o] + (double)b[o];
  out[(size_t)n*10 + o] = (float)r;
}

extern "C" void kernel_launch(void* const* d_in, const int* in_sizes, int n_in,
                              void* d_out, int out_size, void* d_ws, size_t ws_size,
                              hipStream_t stream) {
  const float* x   = (const float*)d_in[0];
  const float* w1  = (const float*)d_in[1];
  const float* g1  = (const float*)d_in[2];
  const float* b1  = (const float*)d_in[3];
  const float* w2  = (const float*)d_in[4];
  const float* g2  = (const float*)d_in[5];
  const float* b2  = (const float*)d_in[6];
  const float* w3  = (const float*)d_in[7];
  const float* g3  = (const float*)d_in[8];
  const float* b3  = (const float*)d_in[9];
  const float* w4  = (const float*)d_in[10];
  const float* g4  = (const float*)d_in[11];
  const float* b4  = (const float*)d_in[12];
  const float* w5  = (const float*)d_in[13];
  const float* g5  = (const float*)d_in[14];
  const float* b5  = (const float*)d_in[15];
  const float* w6  = (const float*)d_in[16];
  const float* g6  = (const float*)d_in[17];
  const float* b6  = (const float*)d_in[18];
  const float* wf1 = (const float*)d_in[19];
  const float* gf1 = (const float*)d_in[20];
  const float* bf1 = (const float*)d_in[21];
  const float* wf2 = (const float*)d_in[22];
  const float* bias2=(const float*)d_in[23];
  const float* gf2 = (const float*)d_in[24];
  const float* bf2 = (const float*)d_in[25];
  float* out = (float*)d_out;

  char* ws = (char*)d_ws;
  size_t off = 0;
  auto alloc = [&](size_t bytes)->char*{ char* p = ws + off; off = (off + bytes + 255) & ~(size_t)255; return p; };

  uint32_t* wb2  = (uint32_t*)alloc(4608ull*4);
  uint32_t* wb3  = (uint32_t*)alloc(9216ull*4);
  uint32_t* wb4  = (uint32_t*)alloc(18432ull*4);
  uint32_t* wb5  = (uint32_t*)alloc(36864ull*4);
  uint32_t* wb6  = (uint32_t*)alloc(73728ull*4);
  uint32_t* wf1b = (uint32_t*)alloc(262144ull*4);
  uint32_t* wf2b = (uint32_t*)alloc(320ull*4);
  double*   part = (double*)  alloc(128ull*2048*2*8);
  long long* pll = (long long*)alloc(512ull*8*2*8);
  double*   Abuf = (double*)  alloc(1024ull*8);
  double*   Bbuf = (double*)  alloc(1024ull*8);
  uint32_t* bitsA= (uint32_t*)alloc(1048576ull*4);
  uint32_t* bitsB= (uint32_t*)alloc(262144ull*4);
  int16_t*  conv = (int16_t*) alloc(16777216ull*2);

  // pack weights
  k_pack_conv_w<<<CDIV(4608,256),256,0,stream>>>(w2, wb2, 128, 4);
  k_pack_conv_w<<<CDIV(9216,256),256,0,stream>>>(w3, wb3, 256, 4);
  k_pack_conv_w<<<CDIV(18432,256),256,0,stream>>>(w4, wb4, 256, 8);
  k_pack_conv_w<<<CDIV(36864,256),256,0,stream>>>(w5, wb5, 512, 8);
  k_pack_conv_w<<<CDIV(73728,256),256,0,stream>>>(w6, wb6, 512, 16);
  k_pack_fc1_w<<<CDIV(262144,256),256,0,stream>>>(wf1, wf1b);
  k_pack_fc2_w<<<CDIV(320,256),256,0,stream>>>(wf2, wf2b);

  // ---- layer 1 ----
  k_conv1_stats3<<<1024,256,0,stream>>>(x, w1, part);
  k_finalize_partials_p<<<128,256,0,stream>>>(part, g1, b1, Abuf, Bbuf, 2048, 1.0/(256.0*1024.0));
  k_conv1_binarize4<<<1024,256,0,stream>>>(x, w1, Abuf, Bbuf, bitsA);

  // ---- layer 2: conv+pool -> [256,128,16,16] ----
  k_xconv_pool<4,32,32,128,4,8><<<256*32,256,0,stream>>>(bitsA, wb2, conv);
  k_chstats_part<8><<<128*8,256,0,stream>>>(conv, pll, 128, 256);
  k_chstats_fin<<<CDIV(128,64),64,0,stream>>>(pll, g2, b2, Abuf, Bbuf, 128, 8, 1.0/(256.0*256.0));
  k_binarize_pack<<<CDIV(256ull*4*256,256),256,0,stream>>>(conv, Abuf, Bbuf, bitsB, 128, 256);

  // ---- layer 3: conv -> [256,256,16,16] ----
  k_xconv<4,16,16,256,16,8><<<256*16,256,0,stream>>>(bitsB, wb3, conv);
  k_chstats_part<8><<<256*8,256,0,stream>>>(conv, pll, 256, 256);
  k_chstats_fin<<<CDIV(256,64),64,0,stream>>>(pll, g3, b3, Abuf, Bbuf, 256, 8, 1.0/(256.0*256.0));
  k_binarize_pack<<<CDIV(256ull*8*256,256),256,0,stream>>>(conv, Abuf, Bbuf, bitsA, 256, 256);

  // ---- layer 4: conv+pool -> [256,256,8,8] ----
  k_xconv_pool<8,16,16,256,16,8><<<256*16,256,0,stream>>>(bitsA, wb4, conv);
  k_chstats_part<8><<<256*8,256,0,stream>>>(conv, pll, 256, 64);
  k_chstats_fin<<<CDIV(256,64),64,0,stream>>>(pll, g4, b4, Abuf, Bbuf, 256, 8, 1.0/(256.0*64.0));
  k_binarize_pack<<<CDIV(256ull*8*64,256),256,0,stream>>>(conv, Abuf, Bbuf, bitsB, 256, 64);

  // ---- layer 5: conv -> [256,512,8,8] ----
  k_xconv<8,8,8,512,64,8><<<256*8,256,0,stream>>>(bitsB, wb5, conv);
  k_chstats_part<8><<<512*8,256,0,stream>>>(conv, pll, 512, 64);
  k_chstats_fin<<<CDIV(512,64),64,0,stream>>>(pll, g5, b5, Abuf, Bbuf, 512, 8, 1.0/(256.0*64.0));
  k_binarize_pack<<<CDIV(256ull*16*64,256),256,0,stream>>>(conv, Abuf, Bbuf, bitsA, 512, 64);

  // ---- layer 6: conv+pool -> [256,512,4,4] ----
  k_xconv_pool<16,8,8,512,64,8><<<256*8,256,0,stream>>>(bitsA, wb6, conv);
  k_chstats_part<8><<<512*8,256,0,stream>>>(conv, pll, 512, 16);
  k_chstats_fin<<<CDIV(512,64),64,0,stream>>>(pll, g6, b6, Abuf, Bbuf, 512, 8, 1.0/(256.0*16.0));
  k_binarize_pack<<<CDIV(256ull*16*16,256),256,0,stream>>>(conv, Abuf, Bbuf, bitsB, 512, 16);

  // ---- FC1 ----
  k_fc1<<<256*4,256,0,stream>>>(bitsB, wf1b, conv);
  k_fc_stats<<<1024,256,0,stream>>>(conv, gf1, bf1, Abuf, Bbuf);
  k_binpack_fc<<<CDIV(256*32,256),256,0,stream>>>(conv, Abuf, Bbuf, bitsA);

  // ---- FC2 + final BN ----
  k_fc2_out<<<10,256,0,stream>>>(bitsA, wf2b, bias2, gf2, bf2, out);

  (void)in_sizes; (void)n_in; (void)out_size; (void)ws_size;
}